// Round 1
// baseline (481.046 us; speedup 1.0000x reference)
//
#include <hip/hip_runtime.h>
#include <hip/hip_bf16.h>
#include <stdint.h>

#define TOKENS 8192
#define IN_F   4096
#define OUT_F  4096
#define RANK   512

typedef __attribute__((ext_vector_type(8))) __bf16 bf16x8;
typedef __attribute__((ext_vector_type(4))) float f32x4;
typedef __attribute__((ext_vector_type(4))) short short4v;

static __device__ __forceinline__ unsigned short f2bf(float f) {
  union { float f; unsigned u; } v; v.f = f;
  return (unsigned short)((v.u + 0x7FFFu + ((v.u >> 16) & 1u)) >> 16);
}

static __device__ __forceinline__ void gload_lds16(const void* g, void* l) {
  __builtin_amdgcn_global_load_lds(
      (const __attribute__((address_space(1))) unsigned*)g,
      (__attribute__((address_space(3))) unsigned*)l, 16, 0, 0);
}

// ---------------------------------------------------------------------------
// Kernel 0: x f32 -> bf16 (memory-bound, ~30us)
// ---------------------------------------------------------------------------
__global__ __launch_bounds__(256) void convert_x(const float* __restrict__ x,
                                                 unsigned short* __restrict__ xb,
                                                 int n4) {
  int idx = blockIdx.x * blockDim.x + threadIdx.x;
  int stride = gridDim.x * blockDim.x;
  for (int i = idx; i < n4; i += stride) {
    f32x4 v = ((const f32x4*)x)[i];
    short4v o;
    o.x = (short)f2bf(v.x);
    o.y = (short)f2bf(v.y);
    o.z = (short)f2bf(v.z);
    o.w = (short)f2bf(v.w);
    ((short4v*)xb)[i] = o;
  }
}

// ---------------------------------------------------------------------------
// Kernel 1: build combined weight
//   M[o,i] = q[o,i]*scale + min_val + sum_r U[o,r]*S[r]*V[i,r]   (bf16 out)
// 128x128 tile, K=RANK=512, BK=64, 4 waves, reg-staged f32->bf16 conversion.
// ---------------------------------------------------------------------------
__global__ __launch_bounds__(256) void build_m(const float* __restrict__ U,
                                               const float* __restrict__ V,
                                               const float* __restrict__ S,
                                               const int* __restrict__ q,
                                               const float* __restrict__ scale_p,
                                               const float* __restrict__ minv_p,
                                               unsigned short* __restrict__ M) {
  __shared__ unsigned short lA[128 * 64];  // U tile   [row=o][k=r]
  __shared__ unsigned short lB[128 * 64];  // (V*S)^T-ish tile [row=i][k=r]
  const int tid  = threadIdx.x;
  const int wid  = tid >> 6;
  const int lane = tid & 63;
  const int bm = blockIdx.x >> 5;  // o-tile (OUT_F/128 = 32)
  const int bn = blockIdx.x & 31;  // i-tile (IN_F/128 = 32)
  const int wm = (wid >> 1) * 64;
  const int wn = (wid & 1) * 64;

  f32x4 acc[4][4] = {};

  const int sr = tid >> 4;         // 0..15 row within 16-row stripe
  const int sc = (tid & 15) * 4;   // 0..60 col (f32x4 chunk)

  for (int k0 = 0; k0 < RANK; k0 += 64) {
    __syncthreads();
#pragma unroll
    for (int p = 0; p < 8; ++p) {
      int row = p * 16 + sr;
      f32x4 uv = *(const f32x4*)&U[(size_t)(bm * 128 + row) * RANK + k0 + sc];
      short4v pa;
      pa.x = (short)f2bf(uv.x); pa.y = (short)f2bf(uv.y);
      pa.z = (short)f2bf(uv.z); pa.w = (short)f2bf(uv.w);
      *(short4v*)&lA[row * 64 + sc] = pa;
      f32x4 vv = *(const f32x4*)&V[(size_t)(bn * 128 + row) * RANK + k0 + sc];
      f32x4 sv = *(const f32x4*)&S[k0 + sc];
      short4v pb;
      pb.x = (short)f2bf(vv.x * sv.x); pb.y = (short)f2bf(vv.y * sv.y);
      pb.z = (short)f2bf(vv.z * sv.z); pb.w = (short)f2bf(vv.w * sv.w);
      *(short4v*)&lB[row * 64 + sc] = pb;
    }
    __syncthreads();
#pragma unroll
    for (int kk = 0; kk < 2; ++kk) {
      bf16x8 af[4], bfr[4];
#pragma unroll
      for (int m = 0; m < 4; ++m)
        af[m] = *(const bf16x8*)&lA[(wm + m * 16 + (lane & 15)) * 64 + kk * 32 + (lane >> 4) * 8];
#pragma unroll
      for (int n = 0; n < 4; ++n)
        bfr[n] = *(const bf16x8*)&lB[(wn + n * 16 + (lane & 15)) * 64 + kk * 32 + (lane >> 4) * 8];
#pragma unroll
      for (int m = 0; m < 4; ++m)
#pragma unroll
        for (int n = 0; n < 4; ++n)
          acc[m][n] = __builtin_amdgcn_mfma_f32_16x16x32_bf16(af[m], bfr[n], acc[m][n], 0, 0, 0);
    }
  }

  const float scale = *scale_p;
  const float minv  = *minv_p;
  const int o0 = bm * 128 + wm;
  const int i0 = bn * 128 + wn;
#pragma unroll
  for (int m = 0; m < 4; ++m) {
#pragma unroll
    for (int n = 0; n < 4; ++n) {
      int col = i0 + n * 16 + (lane & 15);
#pragma unroll
      for (int rr = 0; rr < 4; ++rr) {
        int row = o0 + m * 16 + (lane >> 4) * 4 + rr;
        float dq = (float)q[(size_t)row * IN_F + col] * scale + minv;
        M[(size_t)row * IN_F + col] = f2bf(acc[m][n][rr] + dq);
      }
    }
  }
}

// ---------------------------------------------------------------------------
// Kernel 2: main GEMM  out[t,o] = sum_i xb[t,i] * M[o,i]
// m97 structure: 128x128 tile, BK=64, 4 waves, global_load_lds width=16,
// 2-barrier loop, XCD-bijective swizzle. PRECONV=true: A via gload_lds from
// bf16 x. PRECONV=false: A reg-staged from f32 x with conversion (ws fallback).
// ---------------------------------------------------------------------------
template <bool PRECONV>
__global__ __launch_bounds__(256) void gemm_main(const unsigned short* __restrict__ xb,
                                                 const float* __restrict__ xf,
                                                 const unsigned short* __restrict__ Mw,
                                                 float* __restrict__ out) {
  __shared__ unsigned short lA[128 * 64];  // x tile [t_local][k]
  __shared__ unsigned short lB[128 * 64];  // M tile [o_local][k]
  const int tid  = threadIdx.x;
  const int wid  = tid >> 6;
  const int lane = tid & 63;

  // XCD-aware bijective swizzle (nwg = 2048, divisible by 8)
  const int nwg = gridDim.x;
  const int cpx = nwg >> 3;
  const int swz = (blockIdx.x & 7) * cpx + (blockIdx.x >> 3);
  const int bm = swz >> 5;  // token tile   (TOKENS/128 = 64)
  const int bn = swz & 31;  // out-f tile   (OUT_F/128 = 32)

  const int wm = (wid >> 1) * 64;
  const int wn = (wid & 1) * 64;
  const int row0 = bm * 128;
  const int col0 = bn * 128;

  f32x4 acc[4][4] = {};

  for (int k0 = 0; k0 < IN_F; k0 += 64) {
    __syncthreads();
    if constexpr (PRECONV) {
      // A tile via global_load_lds: wave covers 8 rows per issue, 4 issues
#pragma unroll
      for (int j = 0; j < 4; ++j) {
        int rbase = (wid * 4 + j) * 8;
        const unsigned short* src =
            &xb[(size_t)(row0 + rbase + (lane >> 3)) * IN_F + k0 + (lane & 7) * 8];
        gload_lds16(src, &lA[rbase * 64]);
      }
    } else {
      const int sr = tid >> 4;
      const int sc = (tid & 15) * 4;
#pragma unroll
      for (int p = 0; p < 8; ++p) {
        int row = p * 16 + sr;
        f32x4 v = *(const f32x4*)&xf[(size_t)(row0 + row) * IN_F + k0 + sc];
        short4v pa;
        pa.x = (short)f2bf(v.x); pa.y = (short)f2bf(v.y);
        pa.z = (short)f2bf(v.z); pa.w = (short)f2bf(v.w);
        *(short4v*)&lA[row * 64 + sc] = pa;
      }
    }
    // B tile via global_load_lds
#pragma unroll
    for (int j = 0; j < 4; ++j) {
      int rbase = (wid * 4 + j) * 8;
      const unsigned short* src =
          &Mw[(size_t)(col0 + rbase + (lane >> 3)) * IN_F + k0 + (lane & 7) * 8];
      gload_lds16(src, &lB[rbase * 64]);
    }
    __syncthreads();
#pragma unroll
    for (int kk = 0; kk < 2; ++kk) {
      bf16x8 af[4], bfr[4];
#pragma unroll
      for (int m = 0; m < 4; ++m)
        af[m] = *(const bf16x8*)&lA[(wm + m * 16 + (lane & 15)) * 64 + kk * 32 + (lane >> 4) * 8];
#pragma unroll
      for (int n = 0; n < 4; ++n)
        bfr[n] = *(const bf16x8*)&lB[(wn + n * 16 + (lane & 15)) * 64 + kk * 32 + (lane >> 4) * 8];
#pragma unroll
      for (int m = 0; m < 4; ++m)
#pragma unroll
        for (int n = 0; n < 4; ++n)
          acc[m][n] = __builtin_amdgcn_mfma_f32_16x16x32_bf16(af[m], bfr[n], acc[m][n], 0, 0, 0);
    }
  }

  // epilogue: f32 stores, coalesced across lane&15
#pragma unroll
  for (int m = 0; m < 4; ++m) {
#pragma unroll
    for (int n = 0; n < 4; ++n) {
      int col = col0 + wn + n * 16 + (lane & 15);
#pragma unroll
      for (int rr = 0; rr < 4; ++rr) {
        int row = row0 + wm + m * 16 + (lane >> 4) * 4 + rr;
        out[(size_t)row * OUT_F + col] = acc[m][n][rr];
      }
    }
  }
}

// ---------------------------------------------------------------------------
extern "C" void kernel_launch(void* const* d_in, const int* in_sizes, int n_in,
                              void* d_out, int out_size, void* d_ws, size_t ws_size,
                              hipStream_t stream) {
  const float* x      = (const float*)d_in[0];
  const int*   q      = (const int*)d_in[1];
  const float* scale  = (const float*)d_in[2];
  const float* minv   = (const float*)d_in[3];
  const float* U      = (const float*)d_in[4];
  const float* S      = (const float*)d_in[5];
  const float* V      = (const float*)d_in[6];
  float* out = (float*)d_out;

  const size_t xb_bytes = (size_t)TOKENS * IN_F * 2;  // 64 MB
  const size_t m_bytes  = (size_t)OUT_F * IN_F * 2;   // 32 MB

  unsigned short* xb = nullptr;
  unsigned short* Mw;
  bool preconv;
  if (ws_size >= xb_bytes + m_bytes) {
    xb = (unsigned short*)d_ws;
    Mw = (unsigned short*)((char*)d_ws + xb_bytes);
    preconv = true;
  } else {
    Mw = (unsigned short*)d_ws;  // needs 32 MB
    preconv = false;
  }

  // Build combined weight M (independent of x conversion)
  build_m<<<dim3(1024), dim3(256), 0, stream>>>(U, V, S, q, scale, minv, Mw);

  if (preconv) {
    convert_x<<<dim3(2048), dim3(256), 0, stream>>>(x, (unsigned short*)xb,
                                                    TOKENS * IN_F / 4);
    gemm_main<true><<<dim3(2048), dim3(256), 0, stream>>>(xb, nullptr, Mw, out);
  } else {
    gemm_main<false><<<dim3(2048), dim3(256), 0, stream>>>(nullptr, x, Mw, out);
  }
}

// Round 2
// 329.770 us; speedup vs baseline: 1.4587x; 1.4587x over previous
//
#include <hip/hip_runtime.h>
#include <hip/hip_bf16.h>
#include <stdint.h>

#define TOKENS 8192
#define IN_F   4096
#define OUT_F  4096
#define RANK   512

typedef __attribute__((ext_vector_type(8))) __bf16 bf16x8;
typedef __attribute__((ext_vector_type(4))) float f32x4;
typedef __attribute__((ext_vector_type(4))) short short4v;

static __device__ __forceinline__ unsigned short f2bf(float f) {
  union { float f; unsigned u; } v; v.f = f;
  return (unsigned short)((v.u + 0x7FFFu + ((v.u >> 16) & 1u)) >> 16);
}

static __device__ __forceinline__ void gload_lds16(const void* g, void* l) {
  __builtin_amdgcn_global_load_lds(
      (const __attribute__((address_space(1))) unsigned*)g,
      (__attribute__((address_space(3))) unsigned*)l, 16, 0, 0);
}

// ---------------------------------------------------------------------------
// Kernel 0: x f32 -> bf16
// ---------------------------------------------------------------------------
__global__ __launch_bounds__(256) void convert_x(const float* __restrict__ x,
                                                 unsigned short* __restrict__ xb,
                                                 int n4) {
  int idx = blockIdx.x * blockDim.x + threadIdx.x;
  int stride = gridDim.x * blockDim.x;
  for (int i = idx; i < n4; i += stride) {
    f32x4 v = ((const f32x4*)x)[i];
    short4v o;
    o.x = (short)f2bf(v.x);
    o.y = (short)f2bf(v.y);
    o.z = (short)f2bf(v.z);
    o.w = (short)f2bf(v.w);
    ((short4v*)xb)[i] = o;
  }
}

// ---------------------------------------------------------------------------
// Kernel 1: build combined weight M[o,i] = q*scale + min_val + (U*S)V^T (bf16)
// ---------------------------------------------------------------------------
__global__ __launch_bounds__(256) void build_m(const float* __restrict__ U,
                                               const float* __restrict__ V,
                                               const float* __restrict__ S,
                                               const int* __restrict__ q,
                                               const float* __restrict__ scale_p,
                                               const float* __restrict__ minv_p,
                                               unsigned short* __restrict__ M) {
  __shared__ unsigned short lA[128 * 64];
  __shared__ unsigned short lB[128 * 64];
  const int tid  = threadIdx.x;
  const int wid  = tid >> 6;
  const int lane = tid & 63;
  const int bm = blockIdx.x >> 5;
  const int bn = blockIdx.x & 31;
  const int wm = (wid >> 1) * 64;
  const int wn = (wid & 1) * 64;

  f32x4 acc[4][4] = {};

  const int sr = tid >> 4;
  const int sc = (tid & 15) * 4;

  for (int k0 = 0; k0 < RANK; k0 += 64) {
    __syncthreads();
#pragma unroll
    for (int p = 0; p < 8; ++p) {
      int row = p * 16 + sr;
      f32x4 uv = *(const f32x4*)&U[(size_t)(bm * 128 + row) * RANK + k0 + sc];
      short4v pa;
      pa.x = (short)f2bf(uv.x); pa.y = (short)f2bf(uv.y);
      pa.z = (short)f2bf(uv.z); pa.w = (short)f2bf(uv.w);
      *(short4v*)&lA[row * 64 + sc] = pa;
      f32x4 vv = *(const f32x4*)&V[(size_t)(bn * 128 + row) * RANK + k0 + sc];
      f32x4 sv = *(const f32x4*)&S[k0 + sc];
      short4v pb;
      pb.x = (short)f2bf(vv.x * sv.x); pb.y = (short)f2bf(vv.y * sv.y);
      pb.z = (short)f2bf(vv.z * sv.z); pb.w = (short)f2bf(vv.w * sv.w);
      *(short4v*)&lB[row * 64 + sc] = pb;
    }
    __syncthreads();
#pragma unroll
    for (int kk = 0; kk < 2; ++kk) {
      bf16x8 af[4], bfr[4];
#pragma unroll
      for (int m = 0; m < 4; ++m)
        af[m] = *(const bf16x8*)&lA[(wm + m * 16 + (lane & 15)) * 64 + kk * 32 + (lane >> 4) * 8];
#pragma unroll
      for (int n = 0; n < 4; ++n)
        bfr[n] = *(const bf16x8*)&lB[(wn + n * 16 + (lane & 15)) * 64 + kk * 32 + (lane >> 4) * 8];
#pragma unroll
      for (int m = 0; m < 4; ++m)
#pragma unroll
        for (int n = 0; n < 4; ++n)
          acc[m][n] = __builtin_amdgcn_mfma_f32_16x16x32_bf16(af[m], bfr[n], acc[m][n], 0, 0, 0);
    }
  }

  const float scale = *scale_p;
  const float minv  = *minv_p;
  const int o0 = bm * 128 + wm;
  const int i0 = bn * 128 + wn;
#pragma unroll
  for (int m = 0; m < 4; ++m) {
#pragma unroll
    for (int n = 0; n < 4; ++n) {
      int col = i0 + n * 16 + (lane & 15);
#pragma unroll
      for (int rr = 0; rr < 4; ++rr) {
        int row = o0 + m * 16 + (lane >> 4) * 4 + rr;
        float dq = (float)q[(size_t)row * IN_F + col] * scale + minv;
        M[(size_t)row * IN_F + col] = f2bf(acc[m][n][rr] + dq);
      }
    }
  }
}

// ---------------------------------------------------------------------------
// Kernel 2: main GEMM, 256x256 tile, BK=64, 8 waves, 8-phase (4 phases/K-tile,
// 2-tile buffer parity), counted vmcnt(6), st-swizzled LDS, setprio.
//   out[t,o] = sum_i xb[t,i] * Mw[o,i]
// LDS (dynamic, 128 KiB): buf p at p*65536; A[256][64]bf16 at +0 (half h at
// +h*16384), B[256][64] at +32768. Element (r,cbyte) lives at byte
// r*128 + (cbyte ^ ((r&7)<<4)); staging keeps LDS linear and pre-swizzles the
// per-lane GLOBAL source column (rule #21 both-sides involution).
// Quadrant order per K-tile: ph1=(0,0) ph2=(0,1) ph3=(1,1) ph4=(1,0).
// Staging during tile t: ph1 -> t+1.A1 (other buf); ph2 -> t+2.A0 (A0 last
// read ph1); ph3 -> t+2.B0 (last read ph1); ph4 -> t+2.B1 (last read ph2).
// vmcnt(6) at ph4 leaves exactly t+2's 3 half-tiles in flight; everything of
// tile t+1 is landed before its ph1 ds_reads.
// ---------------------------------------------------------------------------
__global__ __launch_bounds__(512, 2) void gemm256(
    const unsigned short* __restrict__ xb,
    const unsigned short* __restrict__ Mw,
    float* __restrict__ out) {
  extern __shared__ __align__(128) char smem[];
  const int tid  = threadIdx.x;
  const int wid  = tid >> 6;
  const int lane = tid & 63;
  const int wqm  = wid >> 2;  // 0..1 : 64-row slice within a 128x128 quadrant
  const int wqn  = wid & 3;   // 0..3 : 32-col slice

  // XCD-aware bijective swizzle (nwg = 512, divisible by 8)
  const int swz = (blockIdx.x & 7) * 64 + (blockIdx.x >> 3);
  const int bm = swz >> 4;   // 0..31 token tiles
  const int bn = swz & 15;   // 0..15 out-feature tiles
  const int row0 = bm * 256;
  const int col0 = bn * 256;

  // Per-lane ds_read byte offsets within an A/B tile (swizzle folded in).
  int offA[4][2], offB[2][2];
#pragma unroll
  for (int m = 0; m < 4; ++m)
#pragma unroll
    for (int kk = 0; kk < 2; ++kk) {
      int r = wqm * 64 + m * 16 + (lane & 15);
      int cb = kk * 64 + (lane >> 4) * 16;
      offA[m][kk] = r * 128 + (cb ^ ((r & 7) << 4));
    }
#pragma unroll
  for (int n = 0; n < 2; ++n)
#pragma unroll
    for (int kk = 0; kk < 2; ++kk) {
      int r = wqn * 32 + n * 16 + (lane & 15);
      int cb = kk * 64 + (lane >> 4) * 16;
      offB[n][kk] = r * 128 + (cb ^ ((r & 7) << 4));
    }

  // Pre-swizzled global source column (elements) for staging.
  const int sco = (((lane & 7) ^ (lane >> 3)) << 3);
  const int srw = lane >> 3;

  // Stage one 128x64 bf16 half-tile: src rows [g0,g0+128), k cols [k0,k0+64)
  // into LDS bytes [lb, lb+16384), linear dest (wave-uniform base + lane*16).
  auto STAGE = [&](const unsigned short* __restrict__ src, int g0, int k0,
                   unsigned lb) {
#pragma unroll
    for (int j = 0; j < 2; ++j) {
      int r = (wid * 2 + j) * 8;
      const unsigned short* g =
          src + (size_t)(g0 + r + srw) * IN_F + k0 + sco;
      gload_lds16(g, smem + lb + r * 128);
    }
  };

  f32x4 acc[4][4][2] = {};  // [quadrant][m][n]

  // ---- prologue: tile0 all 4 halves -> buf0; tile1 A0,B0,B1 -> buf1 ----
  STAGE(xb, row0,       0, 0u);          // t0 A0
  STAGE(Mw, col0,       0, 32768u);      // t0 B0
  STAGE(Mw, col0 + 128, 0, 49152u);      // t0 B1
  STAGE(xb, row0 + 128, 0, 16384u);      // t0 A1
  STAGE(xb, row0,       64, 65536u);     // t1 A0
  STAGE(Mw, col0,       64, 98304u);     // t1 B0
  STAGE(Mw, col0 + 128, 64, 114688u);    // t1 B1
  asm volatile("s_waitcnt vmcnt(6)");    // tile0 landed; t1 A0/B0/B1 in flight
  __builtin_amdgcn_sched_barrier(0);
  __builtin_amdgcn_s_barrier();

  const int nK = IN_F / 64;  // 64
  bf16x8 a[4][2], b0[2][2], b1[2][2];

  for (int t = 0; t < nK; ++t) {
    const unsigned pb = (unsigned)(t & 1) * 65536u;
    const unsigned qb = 65536u - pb;
    const int k1 = (t + 1) * 64;
    const int k2 = (t + 2) * 64;

    // ================= phase 1 : Q(0,0) =================
#pragma unroll
    for (int m = 0; m < 4; ++m)
#pragma unroll
      for (int kk = 0; kk < 2; ++kk)
        a[m][kk] = *(const bf16x8*)(smem + pb + offA[m][kk]);
#pragma unroll
    for (int n = 0; n < 2; ++n)
#pragma unroll
      for (int kk = 0; kk < 2; ++kk)
        b0[n][kk] = *(const bf16x8*)(smem + pb + 32768u + offB[n][kk]);
    if (t + 1 < nK) STAGE(xb, row0 + 128, k1, qb + 16384u);  // t+1 A1
    __builtin_amdgcn_s_barrier();
    asm volatile("s_waitcnt lgkmcnt(0)");
    __builtin_amdgcn_sched_barrier(0);
    __builtin_amdgcn_s_setprio(1);
#pragma unroll
    for (int m = 0; m < 4; ++m)
#pragma unroll
      for (int n = 0; n < 2; ++n)
#pragma unroll
        for (int kk = 0; kk < 2; ++kk)
          acc[0][m][n] = __builtin_amdgcn_mfma_f32_16x16x32_bf16(
              a[m][kk], b0[n][kk], acc[0][m][n], 0, 0, 0);
    __builtin_amdgcn_s_setprio(0);
    __builtin_amdgcn_sched_barrier(0);
    __builtin_amdgcn_s_barrier();

    // ================= phase 2 : Q(0,1) =================
#pragma unroll
    for (int n = 0; n < 2; ++n)
#pragma unroll
      for (int kk = 0; kk < 2; ++kk)
        b1[n][kk] = *(const bf16x8*)(smem + pb + 49152u + offB[n][kk]);
    if (t + 2 < nK) STAGE(xb, row0, k2, pb);  // t+2 A0
    __builtin_amdgcn_s_barrier();
    asm volatile("s_waitcnt lgkmcnt(0)");
    __builtin_amdgcn_sched_barrier(0);
    __builtin_amdgcn_s_setprio(1);
#pragma unroll
    for (int m = 0; m < 4; ++m)
#pragma unroll
      for (int n = 0; n < 2; ++n)
#pragma unroll
        for (int kk = 0; kk < 2; ++kk)
          acc[1][m][n] = __builtin_amdgcn_mfma_f32_16x16x32_bf16(
              a[m][kk], b1[n][kk], acc[1][m][n], 0, 0, 0);
    __builtin_amdgcn_s_setprio(0);
    __builtin_amdgcn_sched_barrier(0);
    __builtin_amdgcn_s_barrier();

    // ================= phase 3 : Q(1,1) =================
#pragma unroll
    for (int m = 0; m < 4; ++m)
#pragma unroll
      for (int kk = 0; kk < 2; ++kk)
        a[m][kk] = *(const bf16x8*)(smem + pb + 16384u + offA[m][kk]);
    if (t + 2 < nK) STAGE(Mw, col0, k2, pb + 32768u);  // t+2 B0
    __builtin_amdgcn_s_barrier();
    asm volatile("s_waitcnt lgkmcnt(0)");
    __builtin_amdgcn_sched_barrier(0);
    __builtin_amdgcn_s_setprio(1);
#pragma unroll
    for (int m = 0; m < 4; ++m)
#pragma unroll
      for (int n = 0; n < 2; ++n)
#pragma unroll
        for (int kk = 0; kk < 2; ++kk)
          acc[2][m][n] = __builtin_amdgcn_mfma_f32_16x16x32_bf16(
              a[m][kk], b1[n][kk], acc[2][m][n], 0, 0, 0);
    __builtin_amdgcn_s_setprio(0);
    __builtin_amdgcn_sched_barrier(0);
    __builtin_amdgcn_s_barrier();

    // ================= phase 4 : Q(1,0) =================
    if (t + 2 < nK) {
      STAGE(Mw, col0 + 128, k2, pb + 49152u);  // t+2 B1
      asm volatile("s_waitcnt vmcnt(6)");      // tile t+1 fully landed
    } else if (t + 1 < nK) {
      asm volatile("s_waitcnt vmcnt(0)");      // epilogue drain
    }
    __builtin_amdgcn_sched_barrier(0);
    __builtin_amdgcn_s_barrier();
    __builtin_amdgcn_s_setprio(1);
#pragma unroll
    for (int m = 0; m < 4; ++m)
#pragma unroll
      for (int n = 0; n < 2; ++n)
#pragma unroll
        for (int kk = 0; kk < 2; ++kk)
          acc[3][m][n] = __builtin_amdgcn_mfma_f32_16x16x32_bf16(
              a[m][kk], b0[n][kk], acc[3][m][n], 0, 0, 0);
    __builtin_amdgcn_s_setprio(0);
    __builtin_amdgcn_sched_barrier(0);
    __builtin_amdgcn_s_barrier();
  }

  // ---- epilogue ----
  const int qm_[4] = {0, 0, 1, 1};
  const int qn_[4] = {0, 1, 1, 0};
#pragma unroll
  for (int q = 0; q < 4; ++q) {
#pragma unroll
    for (int m = 0; m < 4; ++m) {
#pragma unroll
      for (int n = 0; n < 2; ++n) {
        int col = col0 + qn_[q] * 128 + wqn * 32 + n * 16 + (lane & 15);
#pragma unroll
        for (int rr = 0; rr < 4; ++rr) {
          int row = row0 + qm_[q] * 128 + wqm * 64 + m * 16 + (lane >> 4) * 4 + rr;
          out[(size_t)row * OUT_F + col] = acc[q][m][n][rr];
        }
      }
    }
  }
}

// ---------------------------------------------------------------------------
// Fallback main GEMM (128^2, used only if ws < 96 MB): A reg-staged from f32.
// ---------------------------------------------------------------------------
__global__ __launch_bounds__(256) void gemm_main_f(const float* __restrict__ xf,
                                                   const unsigned short* __restrict__ Mw,
                                                   float* __restrict__ out) {
  __shared__ unsigned short lA[128 * 64];
  __shared__ unsigned short lB[128 * 64];
  const int tid  = threadIdx.x;
  const int wid  = tid >> 6;
  const int lane = tid & 63;
  const int nwg = gridDim.x;
  const int cpx = nwg >> 3;
  const int swz = (blockIdx.x & 7) * cpx + (blockIdx.x >> 3);
  const int bm = swz >> 5;
  const int bn = swz & 31;
  const int wm = (wid >> 1) * 64;
  const int wn = (wid & 1) * 64;
  const int row0 = bm * 128;
  const int col0 = bn * 128;

  f32x4 acc[4][4] = {};

  for (int k0 = 0; k0 < IN_F; k0 += 64) {
    __syncthreads();
    const int sr = tid >> 4;
    const int sc = (tid & 15) * 4;
#pragma unroll
    for (int p = 0; p < 8; ++p) {
      int row = p * 16 + sr;
      f32x4 v = *(const f32x4*)&xf[(size_t)(row0 + row) * IN_F + k0 + sc];
      short4v pa;
      pa.x = (short)f2bf(v.x); pa.y = (short)f2bf(v.y);
      pa.z = (short)f2bf(v.z); pa.w = (short)f2bf(v.w);
      *(short4v*)&lA[row * 64 + sc] = pa;
    }
#pragma unroll
    for (int j = 0; j < 4; ++j) {
      int rbase = (wid * 4 + j) * 8;
      const unsigned short* src =
          &Mw[(size_t)(col0 + rbase + (lane >> 3)) * IN_F + k0 + (lane & 7) * 8];
      gload_lds16(src, &lB[rbase * 64]);
    }
    __syncthreads();
#pragma unroll
    for (int kk = 0; kk < 2; ++kk) {
      bf16x8 af[4], bfr[4];
#pragma unroll
      for (int m = 0; m < 4; ++m)
        af[m] = *(const bf16x8*)&lA[(wm + m * 16 + (lane & 15)) * 64 + kk * 32 + (lane >> 4) * 8];
#pragma unroll
      for (int n = 0; n < 4; ++n)
        bfr[n] = *(const bf16x8*)&lB[(wn + n * 16 + (lane & 15)) * 64 + kk * 32 + (lane >> 4) * 8];
#pragma unroll
      for (int m = 0; m < 4; ++m)
#pragma unroll
        for (int n = 0; n < 4; ++n)
          acc[m][n] = __builtin_amdgcn_mfma_f32_16x16x32_bf16(af[m], bfr[n], acc[m][n], 0, 0, 0);
    }
  }

#pragma unroll
  for (int m = 0; m < 4; ++m) {
#pragma unroll
    for (int n = 0; n < 4; ++n) {
      int col = col0 + wn + n * 16 + (lane & 15);
#pragma unroll
      for (int rr = 0; rr < 4; ++rr) {
        int row = row0 + wm + m * 16 + (lane >> 4) * 4 + rr;
        out[(size_t)row * OUT_F + col] = acc[m][n][rr];
      }
    }
  }
}

// ---------------------------------------------------------------------------
extern "C" void kernel_launch(void* const* d_in, const int* in_sizes, int n_in,
                              void* d_out, int out_size, void* d_ws, size_t ws_size,
                              hipStream_t stream) {
  const float* x      = (const float*)d_in[0];
  const int*   q      = (const int*)d_in[1];
  const float* scale  = (const float*)d_in[2];
  const float* minv   = (const float*)d_in[3];
  const float* U      = (const float*)d_in[4];
  const float* S      = (const float*)d_in[5];
  const float* V      = (const float*)d_in[6];
  float* out = (float*)d_out;

  const size_t xb_bytes = (size_t)TOKENS * IN_F * 2;  // 64 MB
  const size_t m_bytes  = (size_t)OUT_F * IN_F * 2;   // 32 MB

  if (ws_size >= xb_bytes + m_bytes) {
    unsigned short* xbuf = (unsigned short*)d_ws;
    unsigned short* Mw   = (unsigned short*)((char*)d_ws + xb_bytes);
    (void)hipFuncSetAttribute((const void*)gemm256,
                              hipFuncAttributeMaxDynamicSharedMemorySize,
                              131072);
    build_m<<<dim3(1024), dim3(256), 0, stream>>>(U, V, S, q, scale, minv, Mw);
    convert_x<<<dim3(2048), dim3(256), 0, stream>>>(x, xbuf, TOKENS * IN_F / 4);
    gemm256<<<dim3(512), dim3(512), 131072, stream>>>(xbuf, Mw, out);
  } else {
    unsigned short* Mw = (unsigned short*)d_ws;  // needs 32 MB
    build_m<<<dim3(1024), dim3(256), 0, stream>>>(U, V, S, q, scale, minv, Mw);
    gemm_main_f<<<dim3(2048), dim3(256), 0, stream>>>(x, Mw, out);
  }
}